// Round 10
// baseline (97.527 us; speedup 1.0000x reference)
//
#include <hip/hip_runtime.h>

// RoundRobinGate: output = (0.0 scalar, one-hot [2,4096,16,512] f32, same tensor as
// bool->f32). Fully input-independent: 537 MB of zeros + 16,384 ones. Pure store-BW.
//
// R10 = R9 (winning low-occupancy fill shape: 256 blocks x 256 threads, 1 MB
// grid-stride, lane-contiguous float4 stores, branchless wave-uniform hot math)
// with ONE change: nontemporal stores. R6-vs-R7 (only controlled nt comparison,
// identical shape) showed nt +7.7%: no-allocate streaming stores skip L2 thrash.
//
// Flat layout (float32), NTOT = 1 + 2*N1 = 134217729:
//   p = 0 -> scalar 0.0; p in [1,1+N1) -> one-hot (j=p-1); p in [1+N1,1+2N1) -> same.
// Span r (= p>>13, 16384 spans of 8192 floats): span element 0 is never hot
// (hot <= 7935 < 8191); row r's hot sits at span offset hl = hot+1 with i = r & 4095,
// hot = ((i&15)<<9)|(i>>4). Grid stride = 65536 quads = 32 spans exactly, so
// ql = t & 2047 is loop-invariant and r advances by a uniform +32 per iteration.
// Waves (64-aligned) never straddle a span (2048-quad aligned) -> hot math is SALU.
// Tail float p = 134217728 (row 16383 offset 8191) is never hot -> 0.0 (thread 0).

typedef float floatx4 __attribute__((ext_vector_type(4)));

#define NBLK  256u
#define NTHR  (NBLK * 256u)     // 65536 threads; 33554432 quads / NTHR = 512 iters

__global__ void __launch_bounds__(256) rr_gate_fill(floatx4* __restrict__ out4,
                                                    float* __restrict__ out) {
    const unsigned t   = blockIdx.x * 256u + threadIdx.x;
    const unsigned el0 = (t & 2047u) << 2;  // span-element idx of component 0 (invariant)
    unsigned r         = t >> 11;           // span id (wave-uniform), +32 per iter
    floatx4* p         = out4 + t;

#pragma unroll 8
    for (unsigned it = 0; it < 512u; ++it) {
        const unsigned i  = r & 4095u;                          // token row   (SALU)
        const unsigned hl = (((i & 15u) << 9) | (i >> 4)) + 1u; // hot span-off (SALU)
        const unsigned d  = hl - el0;                           // per-thread
        floatx4 v;
        v.x = (d == 0u) ? 1.0f : 0.0f;
        v.y = (d == 1u) ? 1.0f : 0.0f;
        v.z = (d == 2u) ? 1.0f : 0.0f;
        v.w = (d == 3u) ? 1.0f : 0.0f;
        __builtin_nontemporal_store(v, p);
        p += NTHR;
        r += 32u;
    }
    // Final odd element (index 134217728): always 0.
    if (t == 0) {
        out[134217728u] = 0.0f;
    }
}

extern "C" void kernel_launch(void* const* d_in, const int* in_sizes, int n_in,
                              void* d_out, int out_size, void* d_ws, size_t ws_size,
                              hipStream_t stream) {
    (void)d_in; (void)in_sizes; (void)n_in; (void)d_ws; (void)ws_size; (void)out_size;
    hipLaunchKernelGGL(rr_gate_fill, dim3(NBLK), dim3(256), 0, stream,
                       (floatx4*)d_out, (float*)d_out);
}